// Round 6
// baseline (4140.276 us; speedup 1.0000x reference)
//
#include <hip/hip_runtime.h>
#include <hip/hip_bf16.h>

// ---------------------------------------------------------------------------
// LSTM_37847251812594: 2-layer LSTM (B=256, T=64, n_x=512, n_h=1024) + FC+softmax
// Round 6: kill B-ring bank conflicts.
//   - staging ring now stored in MFMA FRAGMENT order: writer lane l fetches
//     (row=l&15, koct=l>>4) so reader lane l's B fragment is at bc + l*16
//     -> contiguous ds_read_b128, conflict-free (was stride-64B, ~16-way)
//   - global coalescing unchanged (same 16 rows x 64B, lane-permuted)
//   - everything else as round 5 (DMA ring, LDS weights, barrier, epilogue)
// ---------------------------------------------------------------------------

typedef short  bf16x8 __attribute__((ext_vector_type(8)));
typedef float  f32x4  __attribute__((ext_vector_type(4)));

#define NHID   1024
#define NBATCH 256
#define NBLK   256
#define HSZE   (NBATCH * NHID)

__device__ __forceinline__ unsigned short f2b(float f) {
    unsigned int u = __builtin_bit_cast(unsigned int, f);
    unsigned int r = (u + 0x7FFFu + ((u >> 16) & 1u)) >> 16;
    return (unsigned short)r;
}
__device__ __forceinline__ float sigmoidf_(float x) {
    return 1.0f / (1.0f + __expf(-x));
}
__device__ __forceinline__ float tanhf_(float x) {
    return 1.0f - 2.0f / (__expf(2.0f * x) + 1.0f);
}

__device__ __forceinline__ void gload_lds16(const void* g, void* l) {
    __builtin_amdgcn_global_load_lds(
        (const __attribute__((address_space(1))) void*)g,
        (__attribute__((address_space(3))) void*)l, 16, 0, 0);
}

// Transpose+convert: W[k][n] fp32 -> Wt[g][n][k] bf16, LDS-tiled 64x64.
__global__ __launch_bounds__(256)
void transpose_w_kernel(const float* __restrict__ w0, const float* __restrict__ w1,
                        const float* __restrict__ w2, const float* __restrict__ w3,
                        unsigned short* __restrict__ dst, int nv) {
    __shared__ unsigned short t[64][65];
    const int gate = blockIdx.z;
    const float* src = (gate == 0) ? w0 : (gate == 1) ? w1 : (gate == 2) ? w2 : w3;
    const int kt = blockIdx.x * 64;
    const int nt = blockIdx.y * 64;
    const int tid = threadIdx.x;
    const int rr = tid >> 6;
    const int cc = tid & 63;
    #pragma unroll
    for (int p = 0; p < 16; ++p) {
        const int row = p * 4 + rr;
        t[cc][row] = f2b(src[(size_t)(kt + row) * NHID + nt + cc]);
    }
    __syncthreads();
    #pragma unroll
    for (int p = 0; p < 16; ++p) {
        const int row = p * 4 + rr;
        dst[((size_t)gate * NHID + nt + row) * nv + kt + cc] = t[row][cc];
    }
}

__global__ void cvt_x_kernel(const float* __restrict__ x, unsigned short* __restrict__ xb, int total4) {
    int idx = blockIdx.x * 256 + threadIdx.x;
    if (idx < total4) {
        float4 v = reinterpret_cast<const float4*>(x)[idx];
        ushort4 o;
        o.x = f2b(v.x); o.y = f2b(v.y); o.z = f2b(v.z); o.w = f2b(v.w);
        reinterpret_cast<ushort4*>(xb)[idx] = o;
    }
}

// Two-level grid barrier (monotone counters, relaxed agent atomics,
// one release fence before arrive + one acquire fence after exit).
__device__ __forceinline__ void grid_sync(unsigned* bar, unsigned gen) {
    __syncthreads();
    if (threadIdx.x == 0) {
        __builtin_amdgcn_fence(__ATOMIC_RELEASE, "agent");
        unsigned* grp  = bar + (blockIdx.x & 7) * 16;
        unsigned* glob = bar + 128;
        unsigned* gctr = bar + 144;
        if (__hip_atomic_fetch_add(grp, 1u, __ATOMIC_RELAXED, __HIP_MEMORY_SCOPE_AGENT)
                == gen * 32u + 31u) {
            if (__hip_atomic_fetch_add(glob, 1u, __ATOMIC_RELAXED, __HIP_MEMORY_SCOPE_AGENT)
                    == gen * 8u + 7u) {
                __hip_atomic_store(gctr, gen + 1u, __ATOMIC_RELAXED, __HIP_MEMORY_SCOPE_AGENT);
            }
        }
        while (__hip_atomic_load(gctr, __ATOMIC_RELAXED, __HIP_MEMORY_SCOPE_AGENT) <= gen) {
            __builtin_amdgcn_s_sleep(2);
        }
        __builtin_amdgcn_fence(__ATOMIC_ACQUIRE, "agent");
    }
    __syncthreads();
}

// Persistent kernel: whole 64-step 2-layer recurrence.
// Block b owns rows r=0..15 (gate r>>2, hidden 4b+(r&3)) of both layers.
// LDS: [0,48K) L0 W, [48K,112K) L1 W, [112K,160K) 3x16K B-staging ring.
// Ring slot: [wave 8][2 groups][16 frag-lanes][16B] in MFMA fragment order.
__global__ __launch_bounds__(512)
void lstm_persist_kernel(const unsigned short* __restrict__ wt0,   // [4][1024][1536]
                         const unsigned short* __restrict__ wt1,   // [4][1024][2048]
                         const unsigned short* __restrict__ xb,    // [256][64][512]
                         const float* __restrict__ bf0, const float* __restrict__ bi0,
                         const float* __restrict__ bc0, const float* __restrict__ bo0,
                         const float* __restrict__ bf1, const float* __restrict__ bi1,
                         const float* __restrict__ bc1, const float* __restrict__ bo1,
                         unsigned short* __restrict__ h0b,   // [2][256][1024] bf16
                         unsigned short* __restrict__ h1b,   // [2][256][1024] bf16
                         float* __restrict__ h1f,            // [256][1024] fp32
                         unsigned* __restrict__ bar) {
    __shared__ __align__(16) char smem[163840];
    unsigned short* lw0 = (unsigned short*)smem;             // 48 KB
    unsigned short* lw1 = (unsigned short*)(smem + 49152);   // 64 KB
    char*           bufs = smem + 114688;                    // 3 x 16 KB ring

    const int tid  = threadIdx.x;
    const int lane = tid & 63;
    const int w    = tid >> 6;     // wave 0..7 -> m rows [32w, 32w+32)
    const int c15  = lane & 15;
    const int kg   = lane >> 4;    // 0..3
    const int b    = blockIdx.x;
    const int bcol = b * 4;

    // ---- stage weights into LDS, fragment order [s][lane][8] ----
    {
        const int row = c15;                     // A-frag row = lane&15
        const int g   = row >> 2;
        const int hid = bcol + (row & 3);
        const unsigned short* s0 = wt0 + ((size_t)g * NHID + hid) * 1536 + kg * 8;
        #pragma unroll
        for (int i = 0; i < 6; ++i) {
            const int s = w + i * 8;
            *(bf16x8*)(lw0 + (size_t)(s * 64 + lane) * 8) = *(const bf16x8*)(s0 + s * 32);
        }
        const unsigned short* s1 = wt1 + ((size_t)g * NHID + hid) * 2048 + kg * 8;
        #pragma unroll
        for (int i = 0; i < 8; ++i) {
            const int s = w + i * 8;
            *(bf16x8*)(lw1 + (size_t)(s * 64 + lane) * 8) = *(const bf16x8*)(s1 + s * 32);
        }
    }

    // biases in registers (gate kg, hidden bcol+0..3)
    f32x4 bias0, bias1;
    {
        const float* bp0 = (kg == 0) ? bf0 : (kg == 1) ? bi0 : (kg == 2) ? bc0 : bo0;
        const float4 v = *(const float4*)(bp0 + bcol);
        bias0[0] = v.x; bias0[1] = v.y; bias0[2] = v.z; bias0[3] = v.w;
        const float* bp1 = (kg == 0) ? bf1 : (kg == 1) ? bi1 : (kg == 2) ? bc1 : bo1;
        const float4 u = *(const float4*)(bp1 + bcol);
        bias1[0] = u.x; bias1[1] = u.y; bias1[2] = u.z; bias1[3] = u.w;
    }
    __syncthreads();

    float c0s[4] = {0.f, 0.f, 0.f, 0.f};
    float c1s[4] = {0.f, 0.f, 0.f, 0.f};
    unsigned gen = 0;

    // Stage chunk c (32 k-elements, this wave's 32 m-rows) into ring slot.
    // FRAGMENT-ORDER write: lane l fetches (row = l&15, koct = l>>4) so the
    // LDS slot holds B fragments at lane*16 -> contiguous conflict-free read.
    auto stage = [&](int slot, int c, int SH,
                     const char* bh, const char* bx, size_t xstr) {
        const int    mr   = lane & 15;
        const size_t colb = (size_t)(lane >> 4) * 16;
        const char* base; size_t rstride; int cl;
        if (c < SH) { base = bh; rstride = 2048; cl = c; }
        else        { base = bx; rstride = xstr; cl = c - SH; }
        const char* g0 = base + (size_t)(w * 32 + mr)      * rstride + (size_t)cl * 64 + colb;
        const char* g1 = base + (size_t)(w * 32 + 16 + mr) * rstride + (size_t)cl * 64 + colb;
        char* l = bufs + slot * 16384 + w * 2048;
        gload_lds16(g0, l);
        gload_lds16(g1, l + 1024);
    };

    // One layer-step: 4-gate GEMM (A from LDS weights, B from DMA-staged ring)
    // + LDS exchange + fused cell epilogue.  exslot: ring slot reused as the
    // f32 exchange buffer (dead at layer end by construction).
    auto layer = [&](const unsigned short* lw, int NC, int SH,
                     const unsigned short* bh_, const unsigned short* bx_, size_t xstr,
                     const f32x4& bias, float* cs, int exslot,
                     unsigned short* hout, float* hfout) {
        const char* bh = (const char*)bh_;
        const char* bx = (const char*)bx_;
        f32x4 acc0 = bias, acc1 = bias;

        stage(0, 0, SH, bh, bx, xstr);
        stage(1, 1, SH, bh, bx, xstr);

        int cslot = 0;   // slot of chunk c
        int sslot = 2;   // slot for chunk c+2
        for (int c = 0; c < NC; ++c) {
            if (c < NC - 1) { asm volatile("s_waitcnt vmcnt(2)" ::: "memory"); }
            else            { asm volatile("s_waitcnt vmcnt(0)" ::: "memory"); }
            if (c + 2 < NC) stage(sslot, c + 2, SH, bh, bx, xstr);
            const char* bc = bufs + cslot * 16384 + w * 2048;
            const bf16x8 a  = *(const bf16x8*)(lw + ((size_t)c * 64 + lane) * 8);
            const bf16x8 b0 = *(const bf16x8*)(bc + lane * 16);
            const bf16x8 b1 = *(const bf16x8*)(bc + 1024 + lane * 16);
            acc0 = __builtin_amdgcn_mfma_f32_16x16x32_bf16(a, b0, acc0, 0, 0, 0);
            acc1 = __builtin_amdgcn_mfma_f32_16x16x32_bf16(a, b1, acc1, 0, 0, 0);
            cslot = (cslot == 2) ? 0 : cslot + 1;
            sslot = (sslot == 2) ? 0 : sslot + 1;
        }

        __syncthreads();
        // exchange: lane (kg,c15): D row = kg*4+j (gate kg, hidden j), col = m-32w
        float* lx  = (float*)(bufs + exslot * 16384);
        float* lxw = lx + w * 512;
        #pragma unroll
        for (int j = 0; j < 4; ++j) {
            lxw[(kg * 4 + j) * 32 + c15]      = acc0[j];
            lxw[(kg * 4 + j) * 32 + 16 + c15] = acc1[j];
        }
        __syncthreads();
        // epilogue: thread t<256 owns m=t, all 4 hidden cells; packed 8-B store
        if (tid < 256) {
            const int w2  = tid >> 5;
            const int col = tid & 31;
            const float* L = lx + w2 * 512;
            float hv[4];
            #pragma unroll
            for (int hl = 0; hl < 4; ++hl) {
                const float fs = L[(0 * 4 + hl) * 32 + col];
                const float is = L[(1 * 4 + hl) * 32 + col];
                const float gs = L[(2 * 4 + hl) * 32 + col];
                const float os = L[(3 * 4 + hl) * 32 + col];
                const float fv = sigmoidf_(fs);
                const float iv = sigmoidf_(is);
                const float cv = tanhf_(gs);
                const float ov = sigmoidf_(os);
                const float cc = fv * cs[hl] + iv * cv;
                const float hh = ov * tanhf_(cc);
                cs[hl] = cc;
                hv[hl] = hh;
            }
            ushort4 hb;
            hb.x = f2b(hv[0]); hb.y = f2b(hv[1]); hb.z = f2b(hv[2]); hb.w = f2b(hv[3]);
            *reinterpret_cast<ushort4*>(hout + (size_t)tid * NHID + bcol) = hb;
            if (hfout) {
                float4 hf; hf.x = hv[0]; hf.y = hv[1]; hf.z = hv[2]; hf.w = hv[3];
                *reinterpret_cast<float4*>(hfout + (size_t)tid * NHID + bcol) = hf;
            }
        }
        __syncthreads();   // exchange slot free before next layer's staging
    };

    // software pipeline: interval t does L0[t] and L1[t-1]; 1 grid barrier each
    for (int t = 0; t <= 64; ++t) {
        if (t < 64) {
            const unsigned short* hprev = h0b + (size_t)((t + 1) & 1) * HSZE;  // h0[t-1]
            unsigned short* hout        = h0b + (size_t)(t & 1) * HSZE;        // h0[t]
            layer(lw0, 48, 32, hprev, xb + (size_t)t * 512, (size_t)64 * 512 * 2,
                  bias0, c0s, /*exslot=*/0, hout, nullptr);
        }
        if (t >= 1) {
            const int u = t - 1;
            const unsigned short* h1prev = h1b + (size_t)((u + 1) & 1) * HSZE; // h1[u-1]
            const unsigned short* h0cur  = h0b + (size_t)(u & 1) * HSZE;       // h0[u]
            unsigned short* hout         = h1b + (size_t)(u & 1) * HSZE;       // h1[u]
            layer(lw1, 64, 32, h1prev, h0cur, (size_t)NHID * 2,
                  bias1, c1s, /*exslot=*/1, hout, (u == 63) ? h1f : nullptr);
        }
        if (t < 64) {
            grid_sync(bar, gen);
            ++gen;
        }
    }
}

// logits = h1 @ W + b : grid (4 n-blocks, 64 m-blocks), 4 m-rows staged in LDS.
__global__ __launch_bounds__(256)
void classifier_kernel(const float* __restrict__ h, const float* __restrict__ W,
                       const float* __restrict__ b, float* __restrict__ logits) {
    __shared__ float hs[4 * 1024];
    const int tid = threadIdx.x;
    const int m0 = blockIdx.y * 4;
    const int n  = blockIdx.x * 256 + tid;
    #pragma unroll
    for (int i = 0; i < 16; ++i)
        hs[i * 256 + tid] = h[(size_t)m0 * NHID + i * 256 + tid];
    __syncthreads();
    if (n < 1000) {
        float a0 = 0.f, a1 = 0.f, a2 = 0.f, a3 = 0.f;
        #pragma unroll 8
        for (int k = 0; k < NHID; ++k) {
            const float wv = W[(size_t)k * 1000 + n];
            a0 = fmaf(hs[k], wv, a0);
            a1 = fmaf(hs[1024 + k], wv, a1);
            a2 = fmaf(hs[2048 + k], wv, a2);
            a3 = fmaf(hs[3072 + k], wv, a3);
        }
        const float bv = b[n];
        logits[(size_t)(m0 + 0) * 1000 + n] = a0 + bv;
        logits[(size_t)(m0 + 1) * 1000 + n] = a1 + bv;
        logits[(size_t)(m0 + 2) * 1000 + n] = a2 + bv;
        logits[(size_t)(m0 + 3) * 1000 + n] = a3 + bv;
    }
}

__global__ void softmax_kernel(const float* __restrict__ logits, float* __restrict__ pred) {
    __shared__ float red[256];
    const int m = blockIdx.x;
    const int t = threadIdx.x;
    const float* lr = logits + (size_t)m * 1000;
    float mx = -3.4e38f;
    for (int i = t; i < 1000; i += 256) mx = fmaxf(mx, lr[i]);
    red[t] = mx; __syncthreads();
    for (int off = 128; off > 0; off >>= 1) {
        if (t < off) red[t] = fmaxf(red[t], red[t + off]);
        __syncthreads();
    }
    mx = red[0];
    __syncthreads();
    float sm = 0.0f;
    for (int i = t; i < 1000; i += 256) sm += __expf(lr[i] - mx);
    red[t] = sm; __syncthreads();
    for (int off = 128; off > 0; off >>= 1) {
        if (t < off) red[t] += red[t + off];
        __syncthreads();
    }
    const float inv = 1.0f / red[0];
    for (int i = t; i < 1000; i += 256)
        pred[(size_t)m * 1000 + i] = __expf(lr[i] - mx) * inv;
}

extern "C" void kernel_launch(void* const* d_in, const int* in_sizes, int n_in,
                              void* d_out, int out_size, void* d_ws, size_t ws_size,
                              hipStream_t stream) {
    (void)in_sizes; (void)n_in; (void)out_size; (void)ws_size;
    const float* x = (const float*)d_in[0];
    const float* W0[4] = {(const float*)d_in[1], (const float*)d_in[2], (const float*)d_in[3], (const float*)d_in[4]};
    const float* B0[4] = {(const float*)d_in[5], (const float*)d_in[6], (const float*)d_in[7], (const float*)d_in[8]};
    const float* W1[4] = {(const float*)d_in[9], (const float*)d_in[10], (const float*)d_in[11], (const float*)d_in[12]};
    const float* B1[4] = {(const float*)d_in[13], (const float*)d_in[14], (const float*)d_in[15], (const float*)d_in[16]};
    const float* Wc = (const float*)d_in[17];
    const float* bc = (const float*)d_in[18];
    float* out = (float*)d_out;

    char* ws = (char*)d_ws;
    size_t off = 0;
    auto alloc = [&](size_t bytes) -> char* {
        char* p = ws + off;
        off += (bytes + 255) & ~(size_t)255;
        return p;
    };
    unsigned short* wt0 = (unsigned short*)alloc((size_t)4 * NHID * 1536 * 2);
    unsigned short* wt1 = (unsigned short*)alloc((size_t)4 * NHID * 2048 * 2);
    unsigned short* xb  = (unsigned short*)alloc((size_t)NBATCH * 64 * 512 * 2);
    char* hstates = ws + off;
    unsigned short* h0b = (unsigned short*)alloc((size_t)2 * HSZE * 2);
    unsigned short* h1b = (unsigned short*)alloc((size_t)2 * HSZE * 2);
    size_t hstate_bytes = (size_t)((char*)h1b + (size_t)2 * HSZE * 2 - hstates);
    float* h1f = (float*)alloc((size_t)HSZE * 4);
    unsigned* bar = (unsigned*)alloc(1024);

    hipMemsetAsync(hstates, 0, hstate_bytes, stream);
    hipMemsetAsync(bar, 0, 1024, stream);

    transpose_w_kernel<<<dim3(1536 / 64, 16, 4), 256, 0, stream>>>(
        W0[0], W0[1], W0[2], W0[3], wt0, 1536);
    transpose_w_kernel<<<dim3(2048 / 64, 16, 4), 256, 0, stream>>>(
        W1[0], W1[1], W1[2], W1[3], wt1, 2048);
    cvt_x_kernel<<<(NBATCH * 64 * 512 / 4 + 255) / 256, 256, 0, stream>>>(
        x, xb, NBATCH * 64 * 512 / 4);

    lstm_persist_kernel<<<NBLK, 512, 0, stream>>>(
        wt0, wt1, xb,
        B0[0], B0[1], B0[2], B0[3],
        B1[0], B1[1], B1[2], B1[3],
        h0b, h1b, h1f, bar);

    classifier_kernel<<<dim3(4, 64), 256, 0, stream>>>(h1f, Wc, bc, out);
    softmax_kernel<<<NBATCH, 256, 0, stream>>>(out, out + (size_t)NBATCH * 1000);
}

// Round 7
// 2340.109 us; speedup vs baseline: 1.7693x; 1.7693x over previous
//
#include <hip/hip_runtime.h>
#include <hip/hip_bf16.h>

// ---------------------------------------------------------------------------
// LSTM_37847251812594: 2-layer LSTM (B=256, T=64, n_x=512, n_h=1024) + FC+softmax
// Round 7: co-designed ring swizzle (both-sides-or-neither, G21).
//   pos(r,k) = 4r + ((k + (r>>1)) & 3):
//   - writer lane l fetches (row=l>>2, koct=((l&3)-((l>>3)&3))&3): lanes
//     4j..4j+3 still cover row j's full 64-B line (round-5 coalescing)
//   - reader lane l reads pos(l&15, l>>4)*16: per 16-lane quarter positions
//     mod 8 = {0,4,1,5,2,6,3,7}x2 -> conflict-free ds_read_b128
//   (round 5: coalesced global + 8-way LDS conflict; round 6: clean LDS +
//    4x global request amplification; this round: both clean)
// ---------------------------------------------------------------------------

typedef short  bf16x8 __attribute__((ext_vector_type(8)));
typedef float  f32x4  __attribute__((ext_vector_type(4)));

#define NHID   1024
#define NBATCH 256
#define NBLK   256
#define HSZE   (NBATCH * NHID)

__device__ __forceinline__ unsigned short f2b(float f) {
    unsigned int u = __builtin_bit_cast(unsigned int, f);
    unsigned int r = (u + 0x7FFFu + ((u >> 16) & 1u)) >> 16;
    return (unsigned short)r;
}
__device__ __forceinline__ float sigmoidf_(float x) {
    return 1.0f / (1.0f + __expf(-x));
}
__device__ __forceinline__ float tanhf_(float x) {
    return 1.0f - 2.0f / (__expf(2.0f * x) + 1.0f);
}

__device__ __forceinline__ void gload_lds16(const void* g, void* l) {
    __builtin_amdgcn_global_load_lds(
        (const __attribute__((address_space(1))) void*)g,
        (__attribute__((address_space(3))) void*)l, 16, 0, 0);
}

// Transpose+convert: W[k][n] fp32 -> Wt[g][n][k] bf16, LDS-tiled 64x64.
__global__ __launch_bounds__(256)
void transpose_w_kernel(const float* __restrict__ w0, const float* __restrict__ w1,
                        const float* __restrict__ w2, const float* __restrict__ w3,
                        unsigned short* __restrict__ dst, int nv) {
    __shared__ unsigned short t[64][65];
    const int gate = blockIdx.z;
    const float* src = (gate == 0) ? w0 : (gate == 1) ? w1 : (gate == 2) ? w2 : w3;
    const int kt = blockIdx.x * 64;
    const int nt = blockIdx.y * 64;
    const int tid = threadIdx.x;
    const int rr = tid >> 6;
    const int cc = tid & 63;
    #pragma unroll
    for (int p = 0; p < 16; ++p) {
        const int row = p * 4 + rr;
        t[cc][row] = f2b(src[(size_t)(kt + row) * NHID + nt + cc]);
    }
    __syncthreads();
    #pragma unroll
    for (int p = 0; p < 16; ++p) {
        const int row = p * 4 + rr;
        dst[((size_t)gate * NHID + nt + row) * nv + kt + cc] = t[row][cc];
    }
}

__global__ void cvt_x_kernel(const float* __restrict__ x, unsigned short* __restrict__ xb, int total4) {
    int idx = blockIdx.x * 256 + threadIdx.x;
    if (idx < total4) {
        float4 v = reinterpret_cast<const float4*>(x)[idx];
        ushort4 o;
        o.x = f2b(v.x); o.y = f2b(v.y); o.z = f2b(v.z); o.w = f2b(v.w);
        reinterpret_cast<ushort4*>(xb)[idx] = o;
    }
}

// Two-level grid barrier (monotone counters, relaxed agent atomics,
// one release fence before arrive + one acquire fence after exit).
__device__ __forceinline__ void grid_sync(unsigned* bar, unsigned gen) {
    __syncthreads();
    if (threadIdx.x == 0) {
        __builtin_amdgcn_fence(__ATOMIC_RELEASE, "agent");
        unsigned* grp  = bar + (blockIdx.x & 7) * 16;
        unsigned* glob = bar + 128;
        unsigned* gctr = bar + 144;
        if (__hip_atomic_fetch_add(grp, 1u, __ATOMIC_RELAXED, __HIP_MEMORY_SCOPE_AGENT)
                == gen * 32u + 31u) {
            if (__hip_atomic_fetch_add(glob, 1u, __ATOMIC_RELAXED, __HIP_MEMORY_SCOPE_AGENT)
                    == gen * 8u + 7u) {
                __hip_atomic_store(gctr, gen + 1u, __ATOMIC_RELAXED, __HIP_MEMORY_SCOPE_AGENT);
            }
        }
        while (__hip_atomic_load(gctr, __ATOMIC_RELAXED, __HIP_MEMORY_SCOPE_AGENT) <= gen) {
            __builtin_amdgcn_s_sleep(2);
        }
        __builtin_amdgcn_fence(__ATOMIC_ACQUIRE, "agent");
    }
    __syncthreads();
}

// Persistent kernel: whole 64-step 2-layer recurrence.
// Block b owns rows r=0..15 (gate r>>2, hidden 4b+(r&3)) of both layers.
// LDS: [0,48K) L0 W, [48K,112K) L1 W, [112K,160K) 3x16K B-staging ring.
// Ring slot: [wave 8][2 m-groups][16 rows x 4 kocts, swizzled pos][16B].
__global__ __launch_bounds__(512)
void lstm_persist_kernel(const unsigned short* __restrict__ wt0,   // [4][1024][1536]
                         const unsigned short* __restrict__ wt1,   // [4][1024][2048]
                         const unsigned short* __restrict__ xb,    // [256][64][512]
                         const float* __restrict__ bf0, const float* __restrict__ bi0,
                         const float* __restrict__ bc0, const float* __restrict__ bo0,
                         const float* __restrict__ bf1, const float* __restrict__ bi1,
                         const float* __restrict__ bc1, const float* __restrict__ bo1,
                         unsigned short* __restrict__ h0b,   // [2][256][1024] bf16
                         unsigned short* __restrict__ h1b,   // [2][256][1024] bf16
                         float* __restrict__ h1f,            // [256][1024] fp32
                         unsigned* __restrict__ bar) {
    __shared__ __align__(16) char smem[163840];
    unsigned short* lw0 = (unsigned short*)smem;             // 48 KB
    unsigned short* lw1 = (unsigned short*)(smem + 49152);   // 64 KB
    char*           bufs = smem + 114688;                    // 3 x 16 KB ring

    const int tid  = threadIdx.x;
    const int lane = tid & 63;
    const int w    = tid >> 6;     // wave 0..7 -> m rows [32w, 32w+32)
    const int c15  = lane & 15;
    const int kg   = lane >> 4;    // 0..3
    const int b    = blockIdx.x;
    const int bcol = b * 4;

    // ---- stage weights into LDS, fragment order [s][lane][8] ----
    {
        const int row = c15;                     // A-frag row = lane&15
        const int g   = row >> 2;
        const int hid = bcol + (row & 3);
        const unsigned short* s0 = wt0 + ((size_t)g * NHID + hid) * 1536 + kg * 8;
        #pragma unroll
        for (int i = 0; i < 6; ++i) {
            const int s = w + i * 8;
            *(bf16x8*)(lw0 + (size_t)(s * 64 + lane) * 8) = *(const bf16x8*)(s0 + s * 32);
        }
        const unsigned short* s1 = wt1 + ((size_t)g * NHID + hid) * 2048 + kg * 8;
        #pragma unroll
        for (int i = 0; i < 8; ++i) {
            const int s = w + i * 8;
            *(bf16x8*)(lw1 + (size_t)(s * 64 + lane) * 8) = *(const bf16x8*)(s1 + s * 32);
        }
    }

    // biases in registers (gate kg, hidden bcol+0..3)
    f32x4 bias0, bias1;
    {
        const float* bp0 = (kg == 0) ? bf0 : (kg == 1) ? bi0 : (kg == 2) ? bc0 : bo0;
        const float4 v = *(const float4*)(bp0 + bcol);
        bias0[0] = v.x; bias0[1] = v.y; bias0[2] = v.z; bias0[3] = v.w;
        const float* bp1 = (kg == 0) ? bf1 : (kg == 1) ? bi1 : (kg == 2) ? bc1 : bo1;
        const float4 u = *(const float4*)(bp1 + bcol);
        bias1[0] = u.x; bias1[1] = u.y; bias1[2] = u.z; bias1[3] = u.w;
    }
    __syncthreads();

    float c0s[4] = {0.f, 0.f, 0.f, 0.f};
    float c1s[4] = {0.f, 0.f, 0.f, 0.f};
    unsigned gen = 0;

    // Writer side of pos(r,k) = 4r + ((k + (r>>1)) & 3):
    // lane l (= pos) fetches row l>>2, koct ((l&3) - ((l>>3)&3)) & 3.
    // Lanes 4j..4j+3 cover row j's full 64-B line -> round-5 coalescing.
    auto stage = [&](int slot, int c, int SH,
                     const char* bh, const char* bx, size_t xstr) {
        const int    mr   = lane >> 2;
        const int    koct = ((lane & 3) - ((lane >> 3) & 3)) & 3;
        const size_t colb = (size_t)koct * 16;
        const char* base; size_t rstride; int cl;
        if (c < SH) { base = bh; rstride = 2048; cl = c; }
        else        { base = bx; rstride = xstr; cl = c - SH; }
        const char* g0 = base + (size_t)(w * 32 + mr)      * rstride + (size_t)cl * 64 + colb;
        const char* g1 = base + (size_t)(w * 32 + 16 + mr) * rstride + (size_t)cl * 64 + colb;
        char* l = bufs + slot * 16384 + w * 2048;
        gload_lds16(g0, l);
        gload_lds16(g1, l + 1024);
    };

    // Reader side: lane l's B fragment (row=l&15, koct=l>>4) lives at
    // pos(l&15, l>>4)*16. Per 16-lane quarter pos mod 8 hits each residue
    // exactly twice -> conflict-free b128.
    const int bofs = (4 * (lane & 15) + (((lane >> 4) + ((lane >> 1) & 3)) & 3)) * 16;

    // One layer-step: 4-gate GEMM (A from LDS weights, B from DMA-staged ring)
    // + LDS exchange + fused cell epilogue.  exslot: ring slot reused as the
    // f32 exchange buffer (dead at layer end by construction).
    auto layer = [&](const unsigned short* lw, int NC, int SH,
                     const unsigned short* bh_, const unsigned short* bx_, size_t xstr,
                     const f32x4& bias, float* cs, int exslot,
                     unsigned short* hout, float* hfout) {
        const char* bh = (const char*)bh_;
        const char* bx = (const char*)bx_;
        f32x4 acc0 = bias, acc1 = bias;

        stage(0, 0, SH, bh, bx, xstr);
        stage(1, 1, SH, bh, bx, xstr);

        int cslot = 0;   // slot of chunk c
        int sslot = 2;   // slot for chunk c+2
        for (int c = 0; c < NC; ++c) {
            if (c < NC - 1) { asm volatile("s_waitcnt vmcnt(2)" ::: "memory"); }
            else            { asm volatile("s_waitcnt vmcnt(0)" ::: "memory"); }
            if (c + 2 < NC) stage(sslot, c + 2, SH, bh, bx, xstr);
            const char* bc = bufs + cslot * 16384 + w * 2048;
            const bf16x8 a  = *(const bf16x8*)(lw + ((size_t)c * 64 + lane) * 8);
            const bf16x8 b0 = *(const bf16x8*)(bc + bofs);
            const bf16x8 b1 = *(const bf16x8*)(bc + 1024 + bofs);
            acc0 = __builtin_amdgcn_mfma_f32_16x16x32_bf16(a, b0, acc0, 0, 0, 0);
            acc1 = __builtin_amdgcn_mfma_f32_16x16x32_bf16(a, b1, acc1, 0, 0, 0);
            cslot = (cslot == 2) ? 0 : cslot + 1;
            sslot = (sslot == 2) ? 0 : sslot + 1;
        }

        __syncthreads();
        // exchange: lane (kg,c15): D row = kg*4+j (gate kg, hidden j), col = m-32w
        float* lx  = (float*)(bufs + exslot * 16384);
        float* lxw = lx + w * 512;
        #pragma unroll
        for (int j = 0; j < 4; ++j) {
            lxw[(kg * 4 + j) * 32 + c15]      = acc0[j];
            lxw[(kg * 4 + j) * 32 + 16 + c15] = acc1[j];
        }
        __syncthreads();
        // epilogue: thread t<256 owns m=t, all 4 hidden cells; packed 8-B store
        if (tid < 256) {
            const int w2  = tid >> 5;
            const int col = tid & 31;
            const float* L = lx + w2 * 512;
            float hv[4];
            #pragma unroll
            for (int hl = 0; hl < 4; ++hl) {
                const float fs = L[(0 * 4 + hl) * 32 + col];
                const float is = L[(1 * 4 + hl) * 32 + col];
                const float gs = L[(2 * 4 + hl) * 32 + col];
                const float os = L[(3 * 4 + hl) * 32 + col];
                const float fv = sigmoidf_(fs);
                const float iv = sigmoidf_(is);
                const float cv = tanhf_(gs);
                const float ov = sigmoidf_(os);
                const float cc = fv * cs[hl] + iv * cv;
                const float hh = ov * tanhf_(cc);
                cs[hl] = cc;
                hv[hl] = hh;
            }
            ushort4 hb;
            hb.x = f2b(hv[0]); hb.y = f2b(hv[1]); hb.z = f2b(hv[2]); hb.w = f2b(hv[3]);
            *reinterpret_cast<ushort4*>(hout + (size_t)tid * NHID + bcol) = hb;
            if (hfout) {
                float4 hf; hf.x = hv[0]; hf.y = hv[1]; hf.z = hv[2]; hf.w = hv[3];
                *reinterpret_cast<float4*>(hfout + (size_t)tid * NHID + bcol) = hf;
            }
        }
        __syncthreads();   // exchange slot free before next layer's staging
    };

    // software pipeline: interval t does L0[t] and L1[t-1]; 1 grid barrier each
    for (int t = 0; t <= 64; ++t) {
        if (t < 64) {
            const unsigned short* hprev = h0b + (size_t)((t + 1) & 1) * HSZE;  // h0[t-1]
            unsigned short* hout        = h0b + (size_t)(t & 1) * HSZE;        // h0[t]
            layer(lw0, 48, 32, hprev, xb + (size_t)t * 512, (size_t)64 * 512 * 2,
                  bias0, c0s, /*exslot=*/0, hout, nullptr);
        }
        if (t >= 1) {
            const int u = t - 1;
            const unsigned short* h1prev = h1b + (size_t)((u + 1) & 1) * HSZE; // h1[u-1]
            const unsigned short* h0cur  = h0b + (size_t)(u & 1) * HSZE;       // h0[u]
            unsigned short* hout         = h1b + (size_t)(u & 1) * HSZE;       // h1[u]
            layer(lw1, 64, 32, h1prev, h0cur, (size_t)NHID * 2,
                  bias1, c1s, /*exslot=*/1, hout, (u == 63) ? h1f : nullptr);
        }
        if (t < 64) {
            grid_sync(bar, gen);
            ++gen;
        }
    }
}

// logits = h1 @ W + b : grid (4 n-blocks, 64 m-blocks), 4 m-rows staged in LDS.
__global__ __launch_bounds__(256)
void classifier_kernel(const float* __restrict__ h, const float* __restrict__ W,
                       const float* __restrict__ b, float* __restrict__ logits) {
    __shared__ float hs[4 * 1024];
    const int tid = threadIdx.x;
    const int m0 = blockIdx.y * 4;
    const int n  = blockIdx.x * 256 + tid;
    #pragma unroll
    for (int i = 0; i < 16; ++i)
        hs[i * 256 + tid] = h[(size_t)m0 * NHID + i * 256 + tid];
    __syncthreads();
    if (n < 1000) {
        float a0 = 0.f, a1 = 0.f, a2 = 0.f, a3 = 0.f;
        #pragma unroll 8
        for (int k = 0; k < NHID; ++k) {
            const float wv = W[(size_t)k * 1000 + n];
            a0 = fmaf(hs[k], wv, a0);
            a1 = fmaf(hs[1024 + k], wv, a1);
            a2 = fmaf(hs[2048 + k], wv, a2);
            a3 = fmaf(hs[3072 + k], wv, a3);
        }
        const float bv = b[n];
        logits[(size_t)(m0 + 0) * 1000 + n] = a0 + bv;
        logits[(size_t)(m0 + 1) * 1000 + n] = a1 + bv;
        logits[(size_t)(m0 + 2) * 1000 + n] = a2 + bv;
        logits[(size_t)(m0 + 3) * 1000 + n] = a3 + bv;
    }
}

__global__ void softmax_kernel(const float* __restrict__ logits, float* __restrict__ pred) {
    __shared__ float red[256];
    const int m = blockIdx.x;
    const int t = threadIdx.x;
    const float* lr = logits + (size_t)m * 1000;
    float mx = -3.4e38f;
    for (int i = t; i < 1000; i += 256) mx = fmaxf(mx, lr[i]);
    red[t] = mx; __syncthreads();
    for (int off = 128; off > 0; off >>= 1) {
        if (t < off) red[t] = fmaxf(red[t], red[t + off]);
        __syncthreads();
    }
    mx = red[0];
    __syncthreads();
    float sm = 0.0f;
    for (int i = t; i < 1000; i += 256) sm += __expf(lr[i] - mx);
    red[t] = sm; __syncthreads();
    for (int off = 128; off > 0; off >>= 1) {
        if (t < off) red[t] += red[t + off];
        __syncthreads();
    }
    const float inv = 1.0f / red[0];
    for (int i = t; i < 1000; i += 256)
        pred[(size_t)m * 1000 + i] = __expf(lr[i] - mx) * inv;
}

extern "C" void kernel_launch(void* const* d_in, const int* in_sizes, int n_in,
                              void* d_out, int out_size, void* d_ws, size_t ws_size,
                              hipStream_t stream) {
    (void)in_sizes; (void)n_in; (void)out_size; (void)ws_size;
    const float* x = (const float*)d_in[0];
    const float* W0[4] = {(const float*)d_in[1], (const float*)d_in[2], (const float*)d_in[3], (const float*)d_in[4]};
    const float* B0[4] = {(const float*)d_in[5], (const float*)d_in[6], (const float*)d_in[7], (const float*)d_in[8]};
    const float* W1[4] = {(const float*)d_in[9], (const float*)d_in[10], (const float*)d_in[11], (const float*)d_in[12]};
    const float* B1[4] = {(const float*)d_in[13], (const float*)d_in[14], (const float*)d_in[15], (const float*)d_in[16]};
    const float* Wc = (const float*)d_in[17];
    const float* bc = (const float*)d_in[18];
    float* out = (float*)d_out;

    char* ws = (char*)d_ws;
    size_t off = 0;
    auto alloc = [&](size_t bytes) -> char* {
        char* p = ws + off;
        off += (bytes + 255) & ~(size_t)255;
        return p;
    };
    unsigned short* wt0 = (unsigned short*)alloc((size_t)4 * NHID * 1536 * 2);
    unsigned short* wt1 = (unsigned short*)alloc((size_t)4 * NHID * 2048 * 2);
    unsigned short* xb  = (unsigned short*)alloc((size_t)NBATCH * 64 * 512 * 2);
    char* hstates = ws + off;
    unsigned short* h0b = (unsigned short*)alloc((size_t)2 * HSZE * 2);
    unsigned short* h1b = (unsigned short*)alloc((size_t)2 * HSZE * 2);
    size_t hstate_bytes = (size_t)((char*)h1b + (size_t)2 * HSZE * 2 - hstates);
    float* h1f = (float*)alloc((size_t)HSZE * 4);
    unsigned* bar = (unsigned*)alloc(1024);

    hipMemsetAsync(hstates, 0, hstate_bytes, stream);
    hipMemsetAsync(bar, 0, 1024, stream);

    transpose_w_kernel<<<dim3(1536 / 64, 16, 4), 256, 0, stream>>>(
        W0[0], W0[1], W0[2], W0[3], wt0, 1536);
    transpose_w_kernel<<<dim3(2048 / 64, 16, 4), 256, 0, stream>>>(
        W1[0], W1[1], W1[2], W1[3], wt1, 2048);
    cvt_x_kernel<<<(NBATCH * 64 * 512 / 4 + 255) / 256, 256, 0, stream>>>(
        x, xb, NBATCH * 64 * 512 / 4);

    lstm_persist_kernel<<<NBLK, 512, 0, stream>>>(
        wt0, wt1, xb,
        B0[0], B0[1], B0[2], B0[3],
        B1[0], B1[1], B1[2], B1[3],
        h0b, h1b, h1f, bar);

    classifier_kernel<<<dim3(4, 64), 256, 0, stream>>>(h1f, Wc, bc, out);
    softmax_kernel<<<NBATCH, 256, 0, stream>>>(out, out + (size_t)NBATCH * 1000);
}